// Round 6
// baseline (294.940 us; speedup 1.0000x reference)
//
#include <hip/hip_runtime.h>

#define NTOKEN 50257
#define NTOK_PAD 50304   // 786 * 64
#define SB 1024
#define C_LOG2PI 235.2482644909f  // 0.5 * 256 * log(2*pi)

typedef __attribute__((ext_vector_type(8))) short bf16x8;
typedef __attribute__((ext_vector_type(4))) short s16x4;
typedef __attribute__((ext_vector_type(4))) float f32x4;
typedef float f32x4u __attribute__((ext_vector_type(4), aligned(4)));

#define MFMA16(a, b, c) __builtin_amdgcn_mfma_f32_16x16x32_bf16((a), (b), (c), 0, 0, 0)

__device__ __forceinline__ unsigned short f2bf(float f) {
  unsigned int u = __float_as_uint(f);
  u += 0x7fffu + ((u >> 16) & 1u);   // round-to-nearest-even
  return (unsigned short)(u >> 16);
}
__device__ __forceinline__ float bf2f(unsigned short s) {
  return __uint_as_float(((unsigned int)s) << 16);
}

// ---------------- workspace layout (bytes) ----------------
#define HB_OFF   0u            // 1024*256*2 = 524288 (linear)
#define HN_OFF   524288u       // 1024*4
#define DM_OFF   528384u       // 256*4
#define W1B_OFF  529408u       // 65536*2
#define W2B_OFF  660480u       // 65536*2  (end = 791552)

// ---------------- small prep: h, weights, diag ----------------
// grid = 32 (h) + 64 (conv_w) + 64 (diag) = 160 blocks x 256
__global__ __launch_bounds__(256) void prep_all(
    const float* __restrict__ h, const float* __restrict__ W1x,
    const float* __restrict__ W2, short* __restrict__ hb,
    float* __restrict__ hnorm, short* __restrict__ W1b,
    short* __restrict__ W2b, float* __restrict__ dM) {
  const int bid = blockIdx.x;
  const int tid = threadIdx.x;
  if (bid < 32) {
    int row = bid * 32 + (tid >> 3);
    int c0 = (tid & 7) * 32;
    float ss = 0.f;
    #pragma unroll
    for (int g = 0; g < 4; ++g) {
      int c = c0 + g * 8;
      const float4* p = (const float4*)&h[row * 256 + c];
      float4 x = p[0], y = p[1];
      float v[8] = {x.x, x.y, x.z, x.w, y.x, y.y, y.z, y.w};
      bf16x8 o;
      #pragma unroll
      for (int j = 0; j < 8; ++j) { ss += v[j] * v[j]; o[j] = (short)f2bf(v[j]); }
      *(bf16x8*)&hb[row * 256 + c] = o;
    }
    ss += __shfl_xor(ss, 1); ss += __shfl_xor(ss, 2); ss += __shfl_xor(ss, 4);
    if ((tid & 7) == 0) hnorm[row] = ss;
  } else if (bid < 96) {
    int base = ((bid - 32) * 256 + tid) * 4;
    float4 a = *(const float4*)&W1x[base];
    short4 o1;
    o1.x = (short)f2bf(a.x); o1.y = (short)f2bf(a.y);
    o1.z = (short)f2bf(a.z); o1.w = (short)f2bf(a.w);
    *(short4*)&W1b[base] = o1;
    float4 b = *(const float4*)&W2[base];
    short4 o2;
    o2.x = (short)f2bf(b.x); o2.y = (short)f2bf(b.y);
    o2.z = (short)f2bf(b.z); o2.w = (short)f2bf(b.w);
    *(short4*)&W2b[base] = o2;
  } else {
    int j = (bid - 96) * 4 + (tid >> 6);
    int lane = tid & 63;
    float s = 0.f;
    #pragma unroll
    for (int t = 0; t < 4; ++t) {
      int i = lane + t * 64;
      s += W1x[j * 256 + i] * W2[i * 256 + j];
    }
    s += __shfl_xor(s, 1); s += __shfl_xor(s, 2); s += __shfl_xor(s, 4);
    s += __shfl_xor(s, 8); s += __shfl_xor(s, 16); s += __shfl_xor(s, 32);
    if (lane == 0) dM[j] = s;
  }
}

// ---- 64x256 LDS tile (token rows, XOR-swizzled) x 256x256 weights^T ----
// accT[m][n] = MFMA16(Wfrag[m], Tfrag[n]) -> D[wcol][token]:
//   wcol = cb + m*16 + rg + r (contiguous in r), token = n*16 + l15.
__device__ __forceinline__ void mmT(const short* T, const short* __restrict__ W,
                                    int l15, int kof, int cb, f32x4 acc[4][4]) {
  const f32x4 vz = {0.f, 0.f, 0.f, 0.f};
  #pragma unroll
  for (int m = 0; m < 4; ++m)
    #pragma unroll
    for (int n = 0; n < 4; ++n) acc[m][n] = vz;
  #pragma unroll
  for (int s = 0; s < 8; ++s) {
    int k0 = s * 32 + kof;
    int ks = k0 ^ ((l15 & 7) << 3);
    bf16x8 w[4], z[4];
    #pragma unroll
    for (int m = 0; m < 4; ++m)
      w[m] = *(const bf16x8*)&W[(cb + m * 16 + l15) * 256 + k0];
    #pragma unroll
    for (int n = 0; n < 4; ++n)
      z[n] = *(const bf16x8*)&T[(n * 16 + l15) * 256 + ks];
    #pragma unroll
    for (int m = 0; m < 4; ++m)
      #pragma unroll
      for (int n = 0; n < 4; ++n) acc[m][n] = MFMA16(w[m], z[n], acc[m][n]);
  }
}

// ---------------- mega kernel: CNF + log-prob, one block per (tc, stripe) ----
// grid 393*8; bid%8 -> XCD x: stripe = x>>1 (hb rows stripe*256..+256,
// L2-resident per XCD), half = x&1, tc = half*393 + bid/8 (adjacent tc on
// the same XCD -> out write-boundary lines merge in its L2).
__global__ __launch_bounds__(256) void mega_kernel(
    const float* __restrict__ emb, const short* __restrict__ hb,
    const short* __restrict__ W1b, const short* __restrict__ W2b,
    const float* __restrict__ dM, const float* __restrict__ w1t,
    const float* __restrict__ b1, const float* __restrict__ b2,
    const float* __restrict__ hnorm, float* __restrict__ out) {
  __shared__ short z0t[64 * 256];   // 32 KB: z0 (kept intact)
  __shared__ short spt[64 * 256];   // 32 KB: sp, then z1, then patch overlay
  __shared__ float trs[4][64];
  __shared__ float znl[64];
  __shared__ float cbl[64];
  const int bid = blockIdx.x;
  const int x = bid & 7;
  const int stripe = x >> 1;
  const int tc = (x & 1) * 393 + (bid >> 3);
  const int tokbase = tc * 64;

  const int tid = threadIdx.x;
  const int lane = tid & 63, wv = tid >> 6;
  const int l15 = lane & 15, rg = (lane >> 4) * 4, kof = (lane >> 4) * 8;
  const int cb = wv * 64;

  // ---- stage z0: emb fp32 -> bf16 swizzled LDS + token norms ----
  {
    int row = tid >> 2;           // 64 tokens, 4 threads per token
    int c0 = (tid & 3) * 64;
    int gtok = tokbase + row;
    bool ok = gtok < NTOKEN;
    float ss = 0.f;
    #pragma unroll
    for (int g = 0; g < 8; ++g) {
      int c = c0 + g * 8;
      float v[8];
      if (ok) {
        const float4* p = (const float4*)&emb[(size_t)gtok * 256 + c];
        float4 xx = p[0], yy = p[1];
        v[0] = xx.x; v[1] = xx.y; v[2] = xx.z; v[3] = xx.w;
        v[4] = yy.x; v[5] = yy.y; v[6] = yy.z; v[7] = yy.w;
      } else {
        #pragma unroll
        for (int j = 0; j < 8; ++j) v[j] = 0.f;
      }
      bf16x8 o;
      #pragma unroll
      for (int j = 0; j < 8; ++j) { ss += v[j] * v[j]; o[j] = (short)f2bf(v[j]); }
      int blk = (c >> 3) ^ (row & 7);
      *(bf16x8*)&z0t[row * 256 + blk * 8] = o;
    }
    ss += __shfl_xor(ss, 1); ss += __shfl_xor(ss, 2);
    if ((tid & 3) == 0) znl[row] = ss;
  }
  // per-lane wcol-quad constants
  f32x4 b1v[4], dmv[4];
  #pragma unroll
  for (int m = 0; m < 4; ++m) {
    b1v[m] = *(const f32x4*)&b1[cb + m * 16 + rg];
    dmv[m] = *(const f32x4*)&dM[cb + m * 16 + rg];
  }
  __syncthreads();

  f32x4 acc[4][4];

  // ---- CNF pass A: pre0^T = W1 x z0; sp -> spt; tr0 ----
  mmT(z0t, W1b, l15, kof, cb, acc);
  {
    float p[4] = {0.f, 0.f, 0.f, 0.f};
    #pragma unroll
    for (int m = 0; m < 4; ++m)
      #pragma unroll
      for (int n = 0; n < 4; ++n) {
        s16x4 spv;
        #pragma unroll
        for (int r = 0; r < 4; ++r) {
          float pre = acc[m][n][r] + b1v[m][r];
          float e = __expf(-fabsf(pre));
          float rc = __fdividef(1.f, 1.f + e);
          p[n] += ((pre >= 0.f) ? rc : e * rc) * dmv[m][r];
          spv[r] = (short)f2bf(fmaxf(pre, 0.f) + __logf(1.f + e));
        }
        int token = n * 16 + l15;
        int colb = (cb + m * 16 + rg) * 2;
        *(s16x4*)((char*)spt + token * 512 + (colb ^ ((token & 7) << 4))) = spv;
      }
    #pragma unroll
    for (int n = 0; n < 4; ++n) {
      p[n] += __shfl_xor(p[n], 16);
      p[n] += __shfl_xor(p[n], 32);
    }
    if (lane < 16)
      #pragma unroll
      for (int n = 0; n < 4; ++n) trs[wv][n * 16 + l15] = p[n];
  }
  __syncthreads();

  // ---- CNF pass B: f0^T = W2 x sp; then z1 = z0 + 0.5*f0 -> spt ----
  mmT(spt, W2b, l15, kof, cb, acc);
  __syncthreads();   // all waves done READING spt before overwriting it
  {
    f32x4 b2v[4];
    #pragma unroll
    for (int m = 0; m < 4; ++m) b2v[m] = *(const f32x4*)&b2[cb + m * 16 + rg];
    #pragma unroll
    for (int m = 0; m < 4; ++m)
      #pragma unroll
      for (int n = 0; n < 4; ++n) {
        int token = n * 16 + l15;
        int colb = (cb + m * 16 + rg) * 2;
        int off = token * 512 + (colb ^ ((token & 7) << 4));
        s16x4 zv = *(s16x4*)((char*)z0t + off);
        s16x4 ov;
        #pragma unroll
        for (int r = 0; r < 4; ++r) {
          float z0v = bf2f((unsigned short)zv[r]);
          ov[r] = (short)f2bf(z0v + 0.5f * (acc[m][n][r] + b2v[m][r]));
        }
        *(s16x4*)((char*)spt + off) = ov;   // cell owned by this lane
      }
  }
  __syncthreads();

  // ---- CNF pass C: pre1^T = W1 x z1; tr1 ----
  mmT(spt, W1b, l15, kof, cb, acc);
  {
    f32x4 bcv[4];
    #pragma unroll
    for (int m = 0; m < 4; ++m) {
      f32x4 wt = *(const f32x4*)&w1t[cb + m * 16 + rg];
      bcv[m] = b1v[m] + 0.5f * wt;
    }
    float p[4] = {0.f, 0.f, 0.f, 0.f};
    #pragma unroll
    for (int m = 0; m < 4; ++m)
      #pragma unroll
      for (int n = 0; n < 4; ++n)
        #pragma unroll
        for (int r = 0; r < 4; ++r) {
          float pre = acc[m][n][r] + bcv[m][r];
          float e = __expf(-fabsf(pre));
          float rc = __fdividef(1.f, 1.f + e);
          p[n] += ((pre >= 0.f) ? rc : e * rc) * dmv[m][r];
        }
    #pragma unroll
    for (int n = 0; n < 4; ++n) {
      p[n] += __shfl_xor(p[n], 16);
      p[n] += __shfl_xor(p[n], 32);
    }
    if (lane < 16)
      #pragma unroll
      for (int n = 0; n < 4; ++n) trs[wv][n * 16 + l15] += p[n];
  }
  __syncthreads();

  if (tid < 64) {
    float t = trs[0][tid] + trs[1][tid] + trs[2][tid] + trs[3][tid];
    cbl[tid] = -0.5f * znl[tid] - C_LOG2PI + 0.5f * t;
  }
  __syncthreads();

  // ---- logp GEMM: A = hb rows (global, L2-hot), B = z0t (LDS) ----
  {
    const f32x4 vz = {0.f, 0.f, 0.f, 0.f};
    #pragma unroll
    for (int m = 0; m < 4; ++m)
      #pragma unroll
      for (int n = 0; n < 4; ++n) acc[m][n] = vz;
    const int arow0 = stripe * 256 + wv * 64;
    #pragma unroll
    for (int s = 0; s < 8; ++s) {
      int k0 = s * 32 + kof;
      int ks = k0 ^ ((l15 & 7) << 3);
      bf16x8 a[4];
      #pragma unroll
      for (int m = 0; m < 4; ++m)
        a[m] = *(const bf16x8*)&hb[(arow0 + m * 16 + l15) * 256 + k0];
      #pragma unroll
      for (int n = 0; n < 4; ++n) {
        bf16x8 b = *(const bf16x8*)&z0t[(n * 16 + l15) * 256 + ks];
        #pragma unroll
        for (int m = 0; m < 4; ++m) acc[m][n] = MFMA16(a[m], b, acc[m][n]);
      }
    }

    // epilogue: wave-private patch [16][65] f32 (65 % 32 == 1 -> 2-way free)
    float* patch = (float*)((char*)spt + wv * 4160);
    const int l4 = lane & 15, lr4 = lane >> 4;
    #pragma unroll
    for (int m = 0; m < 4; ++m) {
      #pragma unroll
      for (int n = 0; n < 4; ++n)
        #pragma unroll
        for (int r = 0; r < 4; ++r)
          patch[(rg + r) * 65 + n * 16 + l15] = acc[m][n][r];
      #pragma unroll
      for (int q = 0; q < 4; ++q) {
        int lrow = q * 4 + lr4;
        int gr = arow0 + m * 16 + lrow;
        int gt = tokbase + l4 * 4;
        f32x4 v = *(const f32x4*)&patch[lrow * 65 + l4 * 4];
        float hn = hnorm[gr];
        f32x4 cb4 = *(const f32x4*)&cbl[l4 * 4];
        #pragma unroll
        for (int c = 0; c < 4; ++c) v[c] += cb4[c] - 0.5f * hn;
        float* op = out + (size_t)gr * NTOKEN + gt;
        if (gt + 4 <= NTOKEN) {
          *(f32x4u*)op = v;
        } else {
          #pragma unroll
          for (int c = 0; c < 4; ++c)
            if (gt + c < NTOKEN) op[c] = v[c];
        }
      }
    }
  }
}

// ---------------- launcher ----------------
extern "C" void kernel_launch(void* const* d_in, const int* in_sizes, int n_in,
                              void* d_out, int out_size, void* d_ws, size_t ws_size,
                              hipStream_t stream) {
  const float* h   = (const float*)d_in[0];
  const float* emb = (const float*)d_in[1];
  const float* W1x = (const float*)d_in[2];
  const float* w1t = (const float*)d_in[3];
  const float* b1  = (const float*)d_in[4];
  const float* W2  = (const float*)d_in[5];
  const float* b2  = (const float*)d_in[6];
  float* out = (float*)d_out;

  char* ws = (char*)d_ws;
  short* hb    = (short*)(ws + HB_OFF);
  float* hnorm = (float*)(ws + HN_OFF);
  float* dM    = (float*)(ws + DM_OFF);
  short* W1b   = (short*)(ws + W1B_OFF);
  short* W2b   = (short*)(ws + W2B_OFF);

  prep_all<<<160, 256, 0, stream>>>(h, W1x, W2, hb, hnorm, W1b, W2b, dM);
  mega_kernel<<<393 * 8, 256, 0, stream>>>(emb, hb, W1b, W2b, dM, w1t, b1, b2,
                                           hnorm, out);
}

// Round 7
// 210.070 us; speedup vs baseline: 1.4040x; 1.4040x over previous
//
#include <hip/hip_runtime.h>

#define NTOKEN 50257
#define NTOK_PAD 50304   // 786 * 64
#define SB 1024
#define C_LOG2PI 235.2482644909f  // 0.5 * 256 * log(2*pi)

typedef __attribute__((ext_vector_type(8))) short bf16x8;
typedef __attribute__((ext_vector_type(4))) short s16x4;
typedef __attribute__((ext_vector_type(4))) float f32x4;
typedef float f32x4u __attribute__((ext_vector_type(4), aligned(4)));

#define MFMA16(a, b, c) __builtin_amdgcn_mfma_f32_16x16x32_bf16((a), (b), (c), 0, 0, 0)

__device__ __forceinline__ unsigned short f2bf(float f) {
  unsigned int u = __float_as_uint(f);
  u += 0x7fffu + ((u >> 16) & 1u);   // round-to-nearest-even
  return (unsigned short)(u >> 16);
}
__device__ __forceinline__ float bf2f(unsigned short s) {
  return __uint_as_float(((unsigned int)s) << 16);
}
__device__ __forceinline__ void gload16(const void* g, void* l) {
  __builtin_amdgcn_global_load_lds(
      (const __attribute__((address_space(1))) unsigned int*)g,
      (__attribute__((address_space(3))) unsigned int*)l, 16, 0, 0);
}

// ---------------- workspace layout (bytes) ----------------
#define HB_OFF   0u            // 1024*256*2  = 524288 (linear)
#define ZB_OFF   524288u       // 50304*256*2 = 25755648 (pre-swizzled rows)
#define HN_OFF   26279936u     // 1024*4
#define CB_OFF   26284032u     // 50304*4
#define DM_OFF   26485248u     // 256*4
#define W1B_OFF  26486272u     // 65536*2
#define W2B_OFF  26617344u     // 65536*2  (end = 26748416)

// ---------------- prep: h, weights, diag, emb->zb ----------------
// grid = 32 (h) + 64 (conv_w) + 64 (diag) + 1572 (z) = 1732 blocks x 256
__global__ __launch_bounds__(256) void prep_all(
    const float* __restrict__ h, const float* __restrict__ emb,
    const float* __restrict__ W1x, const float* __restrict__ W2,
    short* __restrict__ hb, float* __restrict__ hnorm,
    short* __restrict__ zb, float* __restrict__ cbias,
    short* __restrict__ W1b, short* __restrict__ W2b,
    float* __restrict__ dM) {
  const int bid = blockIdx.x;
  const int tid = threadIdx.x;
  if (bid < 32) {
    // ---- h -> linear bf16 + norms ----
    int row = bid * 32 + (tid >> 3);
    int c0 = (tid & 7) * 32;
    float ss = 0.f;
    #pragma unroll
    for (int g = 0; g < 4; ++g) {
      int c = c0 + g * 8;
      const float4* p = (const float4*)&h[row * 256 + c];
      float4 x = p[0], y = p[1];
      float v[8] = {x.x, x.y, x.z, x.w, y.x, y.y, y.z, y.w};
      bf16x8 o;
      #pragma unroll
      for (int j = 0; j < 8; ++j) { ss += v[j] * v[j]; o[j] = (short)f2bf(v[j]); }
      *(bf16x8*)&hb[row * 256 + c] = o;
    }
    ss += __shfl_xor(ss, 1); ss += __shfl_xor(ss, 2); ss += __shfl_xor(ss, 4);
    if ((tid & 7) == 0) hnorm[row] = ss;
  } else if (bid < 96) {
    // ---- W1x, W2 -> bf16 ----
    int base = ((bid - 32) * 256 + tid) * 4;
    float4 a = *(const float4*)&W1x[base];
    short4 o1;
    o1.x = (short)f2bf(a.x); o1.y = (short)f2bf(a.y);
    o1.z = (short)f2bf(a.z); o1.w = (short)f2bf(a.w);
    *(short4*)&W1b[base] = o1;
    float4 b = *(const float4*)&W2[base];
    short4 o2;
    o2.x = (short)f2bf(b.x); o2.y = (short)f2bf(b.y);
    o2.z = (short)f2bf(b.z); o2.w = (short)f2bf(b.w);
    *(short4*)&W2b[base] = o2;
  } else if (bid < 160) {
    // ---- dM[j] = sum_i W1x[j,i] * W2[i,j] ----
    int j = (bid - 96) * 4 + (tid >> 6);
    int lane = tid & 63;
    float s = 0.f;
    #pragma unroll
    for (int t = 0; t < 4; ++t) {
      int i = lane + t * 64;
      s += W1x[j * 256 + i] * W2[i * 256 + j];
    }
    s += __shfl_xor(s, 1); s += __shfl_xor(s, 2); s += __shfl_xor(s, 4);
    s += __shfl_xor(s, 8); s += __shfl_xor(s, 16); s += __shfl_xor(s, 32);
    if (lane == 0) dM[j] = s;
  } else {
    // ---- emb -> pre-swizzled bf16 zb + cbias init ----
    int row = (bid - 160) * 32 + (tid >> 3);
    int c0 = (tid & 7) * 32;
    bool ok = row < NTOKEN;
    float ss = 0.f;
    #pragma unroll
    for (int g = 0; g < 4; ++g) {
      int c = c0 + g * 8;
      float v[8];
      if (ok) {
        const float4* p = (const float4*)&emb[(size_t)row * 256 + c];
        float4 x = p[0], y = p[1];
        v[0] = x.x; v[1] = x.y; v[2] = x.z; v[3] = x.w;
        v[4] = y.x; v[5] = y.y; v[6] = y.z; v[7] = y.w;
      } else {
        #pragma unroll
        for (int j = 0; j < 8; ++j) v[j] = 0.f;
      }
      bf16x8 o;
      #pragma unroll
      for (int j = 0; j < 8; ++j) { ss += v[j] * v[j]; o[j] = (short)f2bf(v[j]); }
      int blk = (c >> 3) ^ (row & 7);
      *(bf16x8*)&zb[(size_t)row * 256 + blk * 8] = o;
    }
    ss += __shfl_xor(ss, 1); ss += __shfl_xor(ss, 2); ss += __shfl_xor(ss, 4);
    if ((tid & 7) == 0) cbias[row] = -0.5f * ss - C_LOG2PI;
  }
}

// ---- 64x256 LDS tile (token rows, XOR-swizzled) x 256x256 weights^T ----
// accT[m][n] = MFMA16(Wfrag[m], Tfrag[n]) -> D[wcol][token]:
//   wcol = cb + m*16 + rg + r (contiguous in r), token = n*16 + l15.
__device__ __forceinline__ void mmT(const short* T, const short* __restrict__ W,
                                    int l15, int kof, int cb, f32x4 acc[4][4]) {
  const f32x4 vz = {0.f, 0.f, 0.f, 0.f};
  #pragma unroll
  for (int m = 0; m < 4; ++m)
    #pragma unroll
    for (int n = 0; n < 4; ++n) acc[m][n] = vz;
  #pragma unroll
  for (int s = 0; s < 8; ++s) {
    int k0 = s * 32 + kof;
    int ks = k0 ^ ((l15 & 7) << 3);
    bf16x8 w[4], z[4];
    #pragma unroll
    for (int m = 0; m < 4; ++m)
      w[m] = *(const bf16x8*)&W[(cb + m * 16 + l15) * 256 + k0];
    #pragma unroll
    for (int n = 0; n < 4; ++n)
      z[n] = *(const bf16x8*)&T[(n * 16 + l15) * 256 + ks];
    #pragma unroll
    for (int m = 0; m < 4; ++m)
      #pragma unroll
      for (int n = 0; n < 4; ++n) acc[m][n] = MFMA16(w[m], z[n], acc[m][n]);
  }
}

// ---------------- CNF: one 32 KB tile, z0 -> sp -> z1 in place ----------------
__global__ __launch_bounds__(256) void cnf_fused(
    const short* __restrict__ zb, const short* __restrict__ W1b,
    const short* __restrict__ W2b, const float* __restrict__ dM,
    const float* __restrict__ w1t, const float* __restrict__ b1,
    const float* __restrict__ b2, float* __restrict__ cbias) {
  __shared__ short zt[64 * 256];    // 32 KB: z0, then sp, then z1
  __shared__ float trs[4][64];
  const int tid = threadIdx.x;
  const int lane = tid & 63, wv = tid >> 6;
  const int l15 = lane & 15, rg = (lane >> 4) * 4, kof = (lane >> 4) * 8;
  const int cb = wv * 64;
  const int tokbase = blockIdx.x * 64;

  // ---- stage z0 tile from pre-swizzled zb: linear, conflict-free ----
  {
    const char* src = (const char*)(zb + (size_t)tokbase * 256);
    char* dst = (char*)zt;
    #pragma unroll
    for (int it = 0; it < 8; ++it) {
      int uoff = wv * 8192 + it * 1024;
      gload16(src + uoff + lane * 16, dst + uoff);
    }
  }
  // per-lane wcol-quad constants
  f32x4 b1v[4], dmv[4];
  #pragma unroll
  for (int m = 0; m < 4; ++m) {
    b1v[m] = *(const f32x4*)&b1[cb + m * 16 + rg];
    dmv[m] = *(const f32x4*)&dM[cb + m * 16 + rg];
  }
  __syncthreads();

  f32x4 acc[4][4];

  // ---- pass A: pre0^T = W1 x z0; tr0; sp -> zt (after barrier) ----
  mmT(zt, W1b, l15, kof, cb, acc);
  __syncthreads();   // all waves done reading z0 before sp overwrites
  {
    float p[4] = {0.f, 0.f, 0.f, 0.f};
    #pragma unroll
    for (int m = 0; m < 4; ++m)
      #pragma unroll
      for (int n = 0; n < 4; ++n) {
        s16x4 spv;
        #pragma unroll
        for (int r = 0; r < 4; ++r) {
          float pre = acc[m][n][r] + b1v[m][r];
          float e = __expf(-fabsf(pre));
          float rc = __fdividef(1.f, 1.f + e);
          p[n] += ((pre >= 0.f) ? rc : e * rc) * dmv[m][r];
          spv[r] = (short)f2bf(fmaxf(pre, 0.f) + __logf(1.f + e));
        }
        int token = n * 16 + l15;
        int colb = (cb + m * 16 + rg) * 2;
        *(s16x4*)((char*)zt + token * 512 + (colb ^ ((token & 7) << 4))) = spv;
      }
    #pragma unroll
    for (int n = 0; n < 4; ++n) {
      p[n] += __shfl_xor(p[n], 16);
      p[n] += __shfl_xor(p[n], 32);
    }
    if (lane < 16)
      #pragma unroll
      for (int n = 0; n < 4; ++n) trs[wv][n * 16 + l15] = p[n];
  }
  __syncthreads();

  // ---- pass B: f0^T = W2 x sp; z1 = z0(global zb) + 0.5*f0 -> zt ----
  mmT(zt, W2b, l15, kof, cb, acc);
  __syncthreads();   // all waves done reading sp before z1 overwrites
  {
    f32x4 b2v[4];
    #pragma unroll
    for (int m = 0; m < 4; ++m) b2v[m] = *(const f32x4*)&b2[cb + m * 16 + rg];
    #pragma unroll
    for (int m = 0; m < 4; ++m)
      #pragma unroll
      for (int n = 0; n < 4; ++n) {
        int token = n * 16 + l15;
        int colb = (cb + m * 16 + rg) * 2;
        int off = token * 512 + (colb ^ ((token & 7) << 4));
        // z0 fragment from L2-hot pre-swizzled zb (same offset formula)
        s16x4 zv = *(const s16x4*)((const char*)zb + (size_t)tokbase * 512 + off);
        s16x4 ov;
        #pragma unroll
        for (int r = 0; r < 4; ++r) {
          float z0v = bf2f((unsigned short)zv[r]);
          ov[r] = (short)f2bf(z0v + 0.5f * (acc[m][n][r] + b2v[m][r]));
        }
        *(s16x4*)((char*)zt + off) = ov;   // cell owned by this lane
      }
  }
  __syncthreads();

  // ---- pass C: pre1^T = W1 x z1; tr1 ----
  mmT(zt, W1b, l15, kof, cb, acc);
  {
    f32x4 bcv[4];
    #pragma unroll
    for (int m = 0; m < 4; ++m) {
      f32x4 wt = *(const f32x4*)&w1t[cb + m * 16 + rg];
      bcv[m] = b1v[m] + 0.5f * wt;
    }
    float p[4] = {0.f, 0.f, 0.f, 0.f};
    #pragma unroll
    for (int m = 0; m < 4; ++m)
      #pragma unroll
      for (int n = 0; n < 4; ++n)
        #pragma unroll
        for (int r = 0; r < 4; ++r) {
          float pre = acc[m][n][r] + bcv[m][r];
          float e = __expf(-fabsf(pre));
          float rc = __fdividef(1.f, 1.f + e);
          p[n] += ((pre >= 0.f) ? rc : e * rc) * dmv[m][r];
        }
    #pragma unroll
    for (int n = 0; n < 4; ++n) {
      p[n] += __shfl_xor(p[n], 16);
      p[n] += __shfl_xor(p[n], 32);
    }
    if (lane < 16)
      #pragma unroll
      for (int n = 0; n < 4; ++n) trs[wv][n * 16 + l15] += p[n];
  }
  __syncthreads();

  if (tid < 64) {
    float t = trs[0][tid] + trs[1][tid] + trs[2][tid] + trs[3][tid];
    cbias[tokbase + tid] += 0.5f * t;   // prep initialized; exclusive owner
  }
}

// ---------------- big log-prob GEMM ----------------
// Block: 256 h-rows x 64 tokens (4 waves x 64 rows), 32 KB LDS.
// XCD scheme (WRITE_SIZE-verified 204 MB in round 6): x = bid&7 -> XCD;
// stripe = x>>1 (hb rows stripe*256, L2-resident), half = x&1,
// tc = half*393 + bid>>3 (adjacent tc on same XCD -> boundary-line merge).
__global__ __launch_bounds__(256) void logp_kernel(
    const short* __restrict__ hb, const short* __restrict__ zb,
    const float* __restrict__ hnorm, const float* __restrict__ cbias,
    float* __restrict__ out) {
  __shared__ char smem[32768];
  short* Bz = (short*)smem;
  const int bid = blockIdx.x;   // 3144 = 393 * 8
  const int x = bid & 7;
  const int stripe = x >> 1;
  const int tc = (x & 1) * 393 + (bid >> 3);
  const int tid = threadIdx.x;
  const int lane = tid & 63, wv = tid >> 6;
  const int l15 = lane & 15, rg = (lane >> 4) * 4, kof = (lane >> 4) * 8;

  // stage B tile (64 tokens, pre-swizzled rows): linear, conflict-free
  {
    const char* bsrc = (const char*)(zb + (size_t)tc * 64 * 256);
    #pragma unroll
    for (int it = 0; it < 8; ++it) {
      int uoff = wv * 8192 + it * 1024;
      gload16(bsrc + uoff + lane * 16, smem + uoff);
    }
  }
  __syncthreads();

  const f32x4 vz = {0.f, 0.f, 0.f, 0.f};
  f32x4 acc[4][4];
  #pragma unroll
  for (int m = 0; m < 4; ++m)
    #pragma unroll
    for (int n = 0; n < 4; ++n) acc[m][n] = vz;

  const int arow0 = stripe * 256 + wv * 64;
  #pragma unroll
  for (int s = 0; s < 8; ++s) {
    int k0 = s * 32 + kof;
    int ks = k0 ^ ((l15 & 7) << 3);
    bf16x8 a[4];
    #pragma unroll
    for (int m = 0; m < 4; ++m)
      a[m] = *(const bf16x8*)&hb[(arow0 + m * 16 + l15) * 256 + k0];  // linear
    #pragma unroll
    for (int n = 0; n < 4; ++n) {
      bf16x8 b = *(const bf16x8*)&Bz[(n * 16 + l15) * 256 + ks];
      #pragma unroll
      for (int m = 0; m < 4; ++m) acc[m][n] = MFMA16(a[m], b, acc[m][n]);
    }
  }
  __syncthreads();  // Bz reads done; overlay transpose patches

  // wave-private patch [16][65] f32 (65 % 32 == 1 -> conflict-free reads)
  float* patch = (float*)(smem + wv * 4160);
  const int l4 = lane & 15, lr4 = lane >> 4;
  const int tokbase = tc * 64;
  #pragma unroll
  for (int m = 0; m < 4; ++m) {
    #pragma unroll
    for (int n = 0; n < 4; ++n)
      #pragma unroll
      for (int r = 0; r < 4; ++r)
        patch[(rg + r) * 65 + n * 16 + l15] = acc[m][n][r];
    asm volatile("s_waitcnt lgkmcnt(0)" ::: "memory");
    #pragma unroll
    for (int q = 0; q < 4; ++q) {
      int lrow = q * 4 + lr4;
      int gr = arow0 + m * 16 + lrow;
      int gt = tokbase + l4 * 4;
      f32x4 v = *(const f32x4*)&patch[lrow * 65 + l4 * 4];
      float hn = hnorm[gr];
      f32x4 cb4 = *(const f32x4*)&cbias[gt];
      #pragma unroll
      for (int c = 0; c < 4; ++c) v[c] += cb4[c] - 0.5f * hn;
      float* op = out + (size_t)gr * NTOKEN + gt;
      if (gt + 4 <= NTOKEN) {
        *(f32x4u*)op = v;
      } else {
        #pragma unroll
        for (int c = 0; c < 4; ++c)
          if (gt + c < NTOKEN) op[c] = v[c];
      }
    }
    asm volatile("s_waitcnt lgkmcnt(0)" ::: "memory");
  }
}

// ---------------- launcher ----------------
extern "C" void kernel_launch(void* const* d_in, const int* in_sizes, int n_in,
                              void* d_out, int out_size, void* d_ws, size_t ws_size,
                              hipStream_t stream) {
  const float* h   = (const float*)d_in[0];
  const float* emb = (const float*)d_in[1];
  const float* W1x = (const float*)d_in[2];
  const float* w1t = (const float*)d_in[3];
  const float* b1  = (const float*)d_in[4];
  const float* W2  = (const float*)d_in[5];
  const float* b2  = (const float*)d_in[6];
  float* out = (float*)d_out;

  char* ws = (char*)d_ws;
  short* hb    = (short*)(ws + HB_OFF);
  short* zb    = (short*)(ws + ZB_OFF);
  float* hnorm = (float*)(ws + HN_OFF);
  float* cbias = (float*)(ws + CB_OFF);
  float* dM    = (float*)(ws + DM_OFF);
  short* W1b   = (short*)(ws + W1B_OFF);
  short* W2b   = (short*)(ws + W2B_OFF);

  prep_all<<<160 + NTOK_PAD / 32, 256, 0, stream>>>(h, emb, W1x, W2, hb, hnorm,
                                                    zb, cbias, W1b, W2b, dM);
  cnf_fused<<<NTOK_PAD / 64, 256, 0, stream>>>(zb, W1b, W2b, dM, w1t, b1, b2,
                                               cbias);
  logp_kernel<<<393 * 8, 256, 0, stream>>>(hb, zb, hnorm, cbias, out);
}